// Round 1
// baseline (7707.153 us; speedup 1.0000x reference)
//
#include <hip/hip_runtime.h>
#include <math.h>

#define Bn 64
#define Tn 128
#define TCn 512
#define CEn 64
#define CHn 256
#define TAGSn 50
#define DWPn 640   // word-LSTM input dim padded 612 -> 640

__device__ __forceinline__ float sigf(float x){ return 1.0f/(1.0f+expf(-x)); }

// ---------------------------------------------------------------------------
// CW[d][c][u*4+k] = b_d[k*256+u] + sum_e ceW[c][e]*Wih_d[k*256+u][e]
// grid (100, 2), 256 threads
__global__ void k_prep_cw(const float* __restrict__ ceW,
                          const float* __restrict__ Wf, const float* __restrict__ bf,
                          const float* __restrict__ Wb, const float* __restrict__ bb,
                          float* __restrict__ CWf, float* __restrict__ CWb){
  const int c = blockIdx.x, u = threadIdx.x;
  const float* Wih  = blockIdx.y ? Wb : Wf;
  const float* bias = blockIdx.y ? bb : bf;
  float*       CW   = blockIdx.y ? CWb : CWf;
  __shared__ float ce[CEn];
  if (u < CEn) ce[u] = ceW[c*CEn + u];
  __syncthreads();
  float a[4];
  #pragma unroll
  for (int k=0;k<4;k++){
    const float* wr = Wih + (size_t)(k*CHn+u)*CEn;
    float s = bias[k*CHn+u];
    #pragma unroll 4
    for (int e=0;e<CEn;e++) s += ce[e]*wr[e];
    a[k]=s;
  }
  ((float4*)CW)[c*CHn+u] = make_float4(a[0],a[1],a[2],a[3]);
}

// WT[e][u*4+k] = Whh[k*256+u][e] ; grid (256, 4), 256 threads
__global__ void k_prep_wt(const float* __restrict__ W0, const float* __restrict__ W1,
                          const float* __restrict__ W2, const float* __restrict__ W3,
                          float* __restrict__ T0, float* __restrict__ T1,
                          float* __restrict__ T2, float* __restrict__ T3){
  const int e = blockIdx.x, u = threadIdx.x, w = blockIdx.y;
  const float* Wh = (w==0)?W0:(w==1)?W1:(w==2)?W2:W3;
  float*       Tt = (w==0)?T0:(w==1)?T1:(w==2)?T2:T3;
  float4 v;
  v.x = Wh[(size_t)(0*CHn+u)*CHn + e];
  v.y = Wh[(size_t)(1*CHn+u)*CHn + e];
  v.z = Wh[(size_t)(2*CHn+u)*CHn + e];
  v.w = Wh[(size_t)(3*CHn+u)*CHn + e];
  ((float4*)Tt)[(size_t)e*CHn+u] = v;
}

// pad word Wih (1024,612) -> (1024,640) ; grid (1024,2), 256 threads
__global__ void k_pad(const float* __restrict__ Wf, const float* __restrict__ Wb,
                      float* __restrict__ Pf, float* __restrict__ Pb){
  const int j = blockIdx.x;
  const float* Win  = blockIdx.y ? Wb : Wf;
  float*       Wout = blockIdx.y ? Pb : Pf;
  for (int col=threadIdx.x; col<DWPn; col+=256)
    Wout[(size_t)j*DWPn+col] = (col<612) ? Win[(size_t)j*612+col] : 0.f;
}

// stable-compaction ranks from cmakers only; grid (64,2), 64 threads (1 wave)
__global__ void k_prep_pos(const float* __restrict__ cmf, const float* __restrict__ cmb,
                           int* __restrict__ pf, int* __restrict__ pb){
  const float* cm = blockIdx.y ? cmb : cmf;
  int* pos        = blockIdx.y ? pb : pf;
  const int n = blockIdx.x, lane = threadIdx.x;
  int base = 0;
  for (int c=0;c<TCn/64;c++){
    int t = c*64 + lane;
    bool m = cm[n*TCn+t] != 0.f;
    unsigned long long bal = __ballot(m);
    int before = __popcll(bal & ((1ULL<<lane)-1ULL));
    int r = base + before;
    pos[n*TCn+t] = (m && r < Tn) ? r : -1;
    base += __popcll(bal);
  }
}

// ---------------------------------------------------------------------------
// char LSTM: 64 blocks = 2 dirs x 32 pairs (R=2 rows/block), 256 threads (unit u)
__global__ __launch_bounds__(256)
void k_char_lstm(const int* __restrict__ cmf, const int* __restrict__ cmb,
                 const float* __restrict__ CWf, const float* __restrict__ CWb,
                 const float* __restrict__ WTf, const float* __restrict__ WTb,
                 const int* __restrict__ posf, const int* __restrict__ posb,
                 float* __restrict__ sub){
  const int dir = blockIdx.x >> 5, pr = blockIdx.x & 31;
  const int n0 = pr*2, n1 = n0+1;
  const int u = threadIdx.x;
  const int*    cm  = dir ? cmb : cmf;
  const float4* CW  = (const float4*)(dir ? CWb : CWf);
  const float4* WT  = (const float4*)(dir ? WTb : WTf);
  const int*    pos = dir ? posb : posf;
  const int dofs = dir ? CHn : 0;
  __shared__ float hb[2][2][CHn];
  hb[0][0][u]=0.f; hb[0][1][u]=0.f;
  float c0=0.f, c1=0.f;
  int par=0;
  __syncthreads();
  for (int t=0;t<TCn;t++){
    const int ci0 = cm[n0*TCn+t], ci1 = cm[n1*TCn+t];
    float4 z0 = CW[(size_t)ci0*CHn+u];
    float4 z1 = CW[(size_t)ci1*CHn+u];
    const float* h0 = hb[par][0];
    const float* h1 = hb[par][1];
    #pragma unroll 4
    for (int e=0;e<CHn;e++){
      const float4 wv = WT[(size_t)e*CHn+u];
      const float a = h0[e], b = h1[e];
      z0.x += wv.x*a; z0.y += wv.y*a; z0.z += wv.z*a; z0.w += wv.w*a;
      z1.x += wv.x*b; z1.y += wv.y*b; z1.z += wv.z*b; z1.w += wv.w*b;
    }
    // gates i,f,g,o = (x, y, z, w)
    c0 = sigf(z0.y)*c0 + sigf(z0.x)*tanhf(z0.z);
    const float hn0 = sigf(z0.w)*tanhf(c0);
    c1 = sigf(z1.y)*c1 + sigf(z1.x)*tanhf(z1.z);
    const float hn1 = sigf(z1.w)*tanhf(c1);
    hb[par^1][0][u]=hn0; hb[par^1][1][u]=hn1;
    const int p0 = pos[n0*TCn+t];
    if (p0>=0) sub[(size_t)(n0*Tn+p0)*512 + dofs + u] = hn0;
    const int p1 = pos[n1*TCn+t];
    if (p1>=0) sub[(size_t)(n1*Tn+p1)*512 + dofs + u] = hn1;
    __syncthreads();
    par ^= 1;
  }
}

// ---------------------------------------------------------------------------
// generic fp32 GEMM: C[m][n] = bias[n] + sum_k A[m][k]*W[n][k]
// block tile 128x64, 256 threads, 8x4 micro-tile, K chunk 32.
// blockIdx.z selects (W,bias,C) pair.
__global__ __launch_bounds__(256)
void k_gemm(const float* __restrict__ A, int lda, int K, int ldw,
            const float* __restrict__ W0, const float* __restrict__ W1,
            const float* __restrict__ b0, const float* __restrict__ b1,
            float* __restrict__ C0, float* __restrict__ C1, int ldc){
  const float* W    = blockIdx.z ? W1 : W0;
  const float* bias = blockIdx.z ? b1 : b0;
  float*       C    = blockIdx.z ? C1 : C0;
  const int m0 = blockIdx.x*128, n0 = blockIdx.y*64;
  __shared__ float As[32][132];
  __shared__ float Bs[32][68];
  const int tid = threadIdx.x;
  float acc[8][4];
  #pragma unroll
  for (int i=0;i<8;i++){
    #pragma unroll
    for (int j=0;j<4;j++) acc[i][j]=0.f;
  }
  const int tm = tid & 15, tn = tid >> 4;
  for (int kc=0; kc<K; kc+=32){
    #pragma unroll
    for (int it=0; it<4; it++){
      int fl = tid + it*256; int r = fl>>3; int kq = fl&7;
      float4 v = *(const float4*)(A + (size_t)(m0+r)*lda + kc + kq*4);
      As[kq*4+0][r]=v.x; As[kq*4+1][r]=v.y; As[kq*4+2][r]=v.z; As[kq*4+3][r]=v.w;
    }
    #pragma unroll
    for (int it=0; it<2; it++){
      int fl = tid + it*256; int r = fl>>3; int kq = fl&7;
      float4 v = *(const float4*)(W + (size_t)(n0+r)*ldw + kc + kq*4);
      Bs[kq*4+0][r]=v.x; Bs[kq*4+1][r]=v.y; Bs[kq*4+2][r]=v.z; Bs[kq*4+3][r]=v.w;
    }
    __syncthreads();
    #pragma unroll
    for (int k=0;k<32;k++){
      float a[8], b[4];
      *(float4*)(a)   = *(const float4*)(&As[k][tm*8]);
      *(float4*)(a+4) = *(const float4*)(&As[k][tm*8+4]);
      *(float4*)(b)   = *(const float4*)(&Bs[k][tn*4]);
      #pragma unroll
      for (int i=0;i<8;i++){
        #pragma unroll
        for (int j=0;j<4;j++) acc[i][j] += a[i]*b[j];
      }
    }
    __syncthreads();
  }
  float4 bv = *(const float4*)(bias + n0 + tn*4);
  #pragma unroll
  for (int i=0;i<8;i++){
    float4 o = make_float4(acc[i][0]+bv.x, acc[i][1]+bv.y, acc[i][2]+bv.z, acc[i][3]+bv.w);
    *(float4*)(C + (size_t)(m0+tm*8+i)*ldc + n0 + tn*4) = o;
  }
}

// highway elementwise: sub = g*relu(zt) + (1-g)*sub ; 4096 blocks x 256
__global__ __launch_bounds__(256)
void k_hwelt(const float* __restrict__ hwz, float* __restrict__ sub){
  const int idx = blockIdx.x*256 + threadIdx.x;     // 8192*128 float4s
  const int m = idx >> 7, j4 = idx & 127;
  float4 s  = ((const float4*)sub)[idx];
  float4 zt = ((const float4*)hwz)[(size_t)m*256 + j4];
  float4 zg = ((const float4*)hwz)[(size_t)m*256 + 128 + j4];
  float4 o;
  { float g=sigf(zg.x), tr=fmaxf(zt.x,0.f); o.x = g*tr + (1.f-g)*s.x; }
  { float g=sigf(zg.y), tr=fmaxf(zt.y,0.f); o.y = g*tr + (1.f-g)*s.y; }
  { float g=sigf(zg.z), tr=fmaxf(zt.z,0.f); o.z = g*tr + (1.f-g)*s.z; }
  { float g=sigf(zg.w), tr=fmaxf(zt.w,0.f); o.w = g*tr + (1.f-g)*s.w; }
  ((float4*)sub)[idx] = o;
}

// assemble padded word input w[m] = [we_W[wmap[m]] (100) | sub[m] (512) | 0 (28)]
__global__ void k_wasm(const int* __restrict__ wmap, const float* __restrict__ weW,
                       const float* __restrict__ sub, float* __restrict__ w){
  const int m = blockIdx.x;
  const int wi = wmap[m];
  for (int col=threadIdx.x; col<DWPn; col+=256){
    float v = 0.f;
    if (col < 100)      v = weW[(size_t)wi*100 + col];
    else if (col < 612) v = sub[(size_t)m*512 + (col-100)];
    w[(size_t)m*DWPn + col] = v;
  }
}

// word LSTM: scans over B=64 steps, batch T=128. 64 blocks = 2 dirs x 32 (R=4 rows)
__global__ __launch_bounds__(256)
void k_word_lstm(const float* __restrict__ wXf, const float* __restrict__ wXb,
                 const float* __restrict__ WTf, const float* __restrict__ WTb,
                 float* __restrict__ hout){
  const int dir = blockIdx.x >> 5, q = blockIdx.x & 31;
  const int t0 = q*4;
  const int u = threadIdx.x;
  const float*  wX = dir ? wXb : wXf;
  const float4* WT = (const float4*)(dir ? WTb : WTf);
  __shared__ float hb[2][4][CHn];
  #pragma unroll
  for (int r=0;r<4;r++) hb[0][r][u]=0.f;
  float c[4] = {0.f,0.f,0.f,0.f};
  int par=0;
  __syncthreads();
  for (int s=0;s<64;s++){
    const int n = dir ? (63-s) : s;
    float z[4][4];
    #pragma unroll
    for (int r=0;r<4;r++){
      const float* xr = wX + (size_t)(n*Tn + t0 + r)*1024;
      #pragma unroll
      for (int k=0;k<4;k++) z[r][k] = xr[k*CHn + u];
    }
    const float* h0 = hb[par][0];
    const float* h1 = hb[par][1];
    const float* h2 = hb[par][2];
    const float* h3 = hb[par][3];
    #pragma unroll 2
    for (int e=0;e<CHn;e++){
      const float4 wv = WT[(size_t)e*CHn+u];
      const float a0=h0[e], a1=h1[e], a2=h2[e], a3=h3[e];
      z[0][0]+=wv.x*a0; z[0][1]+=wv.y*a0; z[0][2]+=wv.z*a0; z[0][3]+=wv.w*a0;
      z[1][0]+=wv.x*a1; z[1][1]+=wv.y*a1; z[1][2]+=wv.z*a1; z[1][3]+=wv.w*a1;
      z[2][0]+=wv.x*a2; z[2][1]+=wv.y*a2; z[2][2]+=wv.z*a2; z[2][3]+=wv.w*a2;
      z[3][0]+=wv.x*a3; z[3][1]+=wv.y*a3; z[3][2]+=wv.z*a3; z[3][3]+=wv.w*a3;
    }
    #pragma unroll
    for (int r=0;r<4;r++){
      c[r] = sigf(z[r][1])*c[r] + sigf(z[r][0])*tanhf(z[r][2]);
      const float hn = sigf(z[r][3])*tanhf(c[r]);
      hb[par^1][r][u] = hn;
      hout[(size_t)(n*Tn + t0 + r)*512 + dir*CHn + u] = hn;
    }
    __syncthreads();
    par ^= 1;
  }
}

// em[m][tag] = emb[tag] + sum_k h[m][k]*emW[tag][k] ; 2048 blocks x 256
__global__ void k_em(const float* __restrict__ hout, const float* __restrict__ emW,
                     const float* __restrict__ emb, float* __restrict__ em){
  const int idx = blockIdx.x*256 + threadIdx.x;
  const int m = idx >> 6, tag = idx & 63;
  if (tag >= TAGSn) return;
  const float* hr = hout + (size_t)m*512;
  const float* wr = emW  + (size_t)tag*512;
  float a = emb[tag];
  #pragma unroll 4
  for (int k=0;k<512;k++) a += hr[k]*wr[k];
  em[(size_t)m*TAGSn + tag] = a;
}

// crf[m][a][b] = em[m][b] + trans[a][b] ; 8192 blocks x 256
__global__ __launch_bounds__(256)
void k_crf(const float* __restrict__ em, const float* __restrict__ trans,
           float* __restrict__ out){
  const int m = blockIdx.x;
  __shared__ float er[TAGSn];
  if (threadIdx.x < TAGSn) er[threadIdx.x] = em[(size_t)m*TAGSn + threadIdx.x];
  __syncthreads();
  float* o = out + (size_t)m*2500;
  for (int r=threadIdx.x; r<2500; r+=256)
    o[r] = er[r % TAGSn] + trans[r];
}

// int tail outputs as floats
__global__ void k_tail(const int* __restrict__ tm, const int* __restrict__ ln,
                       const int* __restrict__ tc, float* __restrict__ out){
  const int i = blockIdx.x*256 + threadIdx.x;
  if (i < 8192)       out[i] = (float)tm[i];
  else if (i < 8256)  out[i] = (float)ln[i-8192];
  else if (i < 16448) out[i] = (float)tc[i-8256];
}

// ---------------------------------------------------------------------------
extern "C" void kernel_launch(void* const* d_in, const int* in_sizes, int n_in,
                              void* d_out, int out_size, void* d_ws, size_t ws_size,
                              hipStream_t stream){
  (void)in_sizes; (void)n_in; (void)out_size; (void)ws_size;
  const int*   wmap   = (const int*)d_in[0];
  const int*   cmapsf = (const int*)d_in[1];
  const int*   cmapsb = (const int*)d_in[2];
  const float* cmakf  = (const float*)d_in[3];
  const float* cmakb  = (const float*)d_in[4];
  const int*   tmaps  = (const int*)d_in[5];
  const int*   tmapc  = (const int*)d_in[6];
  const int*   lengths= (const int*)d_in[7];
  const float* ceW    = (const float*)d_in[8];
  const float* fcWih  = (const float*)d_in[9];
  const float* fcWhh  = (const float*)d_in[10];
  const float* fcb    = (const float*)d_in[11];
  const float* bcWih  = (const float*)d_in[12];
  const float* bcWhh  = (const float*)d_in[13];
  const float* bcb    = (const float*)d_in[14];
  const float* weW    = (const float*)d_in[15];
  const float* wfWih  = (const float*)d_in[16];
  const float* wfWhh  = (const float*)d_in[17];
  const float* wfb    = (const float*)d_in[18];
  const float* wbWih  = (const float*)d_in[19];
  const float* wbWhh  = (const float*)d_in[20];
  const float* wbb    = (const float*)d_in[21];
  const float* hwWt   = (const float*)d_in[22];
  const float* hwbt   = (const float*)d_in[23];
  const float* hwWg   = (const float*)d_in[24];
  const float* hwbg   = (const float*)d_in[25];
  const float* emW    = (const float*)d_in[26];
  const float* emb    = (const float*)d_in[27];
  const float* trans  = (const float*)d_in[28];

  // workspace layout (floats)
  float* p = (float*)d_ws;
  size_t o = 0;
  float* CWf  = p + o; o += 100*1024;
  float* CWb  = p + o; o += 100*1024;
  float* WTcf = p + o; o += 256*1024;
  float* WTcb = p + o; o += 256*1024;
  float* WTwf = p + o; o += 256*1024;
  float* WTwb = p + o; o += 256*1024;
  float* Wpf  = p + o; o += 1024*DWPn;
  float* Wpb  = p + o; o += 1024*DWPn;
  int*   posf = (int*)(p + o); o += 64*512;
  int*   posb = (int*)(p + o); o += 64*512;
  float* sub  = p + o; o += (size_t)64*128*512;   // reused later as hout
  float* hwz  = p + o; o += (size_t)8192*1024;    // reused later as wXf
  float* wq   = p + o; o += (size_t)8192*DWPn;
  float* wXb  = p + o; o += (size_t)8192*1024;
  float* em   = p + o; o += (size_t)8192*TAGSn;
  float* wXf  = hwz;   // alias: hwz dead after k_hwelt
  float* hout = sub;   // alias: sub dead after k_wasm

  float* out  = (float*)d_out;

  hipMemsetAsync(sub, 0, (size_t)64*128*512*sizeof(float), stream);

  k_prep_cw <<<dim3(100,2), 256, 0, stream>>>(ceW, fcWih, fcb, bcWih, bcb, CWf, CWb);
  k_prep_wt <<<dim3(256,4), 256, 0, stream>>>(fcWhh, bcWhh, wfWhh, wbWhh, WTcf, WTcb, WTwf, WTwb);
  k_pad     <<<dim3(1024,2), 256, 0, stream>>>(wfWih, wbWih, Wpf, Wpb);
  k_prep_pos<<<dim3(64,2), 64, 0, stream>>>(cmakf, cmakb, posf, posb);

  k_char_lstm<<<64, 256, 0, stream>>>(cmapsf, cmapsb, CWf, CWb, WTcf, WTcb, posf, posb, sub);

  // highway: hwz[:,0:512] = sub@Wt^T+bt ; hwz[:,512:1024] = sub@Wg^T+bg
  k_gemm<<<dim3(64,8,2), 256, 0, stream>>>(sub, 512, 512, 512,
                                           hwWt, hwWg, hwbt, hwbg,
                                           hwz, hwz+512, 1024);
  k_hwelt<<<4096, 256, 0, stream>>>(hwz, sub);

  k_wasm<<<8192, 256, 0, stream>>>(wmap, weW, sub, wq);

  // word input projections: wX_d = w @ Wih_d^T + b_d
  k_gemm<<<dim3(64,16,2), 256, 0, stream>>>(wq, DWPn, DWPn, DWPn,
                                            Wpf, Wpb, wfb, wbb,
                                            wXf, wXb, 1024);

  k_word_lstm<<<64, 256, 0, stream>>>(wXf, wXb, WTwf, WTwb, hout);

  k_em <<<2048, 256, 0, stream>>>(hout, emW, emb, em);
  k_crf<<<8192, 256, 0, stream>>>(em, trans, out);
  k_tail<<<65, 256, 0, stream>>>(tmaps, lengths, tmapc, out + (size_t)20480000);
}

// Round 2
// 5386.429 us; speedup vs baseline: 1.4308x; 1.4308x over previous
//
#include <hip/hip_runtime.h>
#include <hip/hip_fp16.h>
#include <math.h>

#define Bn 64
#define Tn 128
#define TCn 512
#define CEn 64
#define CHn 256
#define TAGSn 50
#define DWPn 640   // word-LSTM input dim padded 612 -> 640

__device__ __forceinline__ float sigf(float x){ return 1.0f/(1.0f+expf(-x)); }

__device__ __forceinline__ unsigned h2u(__half2 h){ union{__half2 h; unsigned u;} v; v.h=h; return v.u; }
__device__ __forceinline__ __half2 u2h(unsigned u){ union{__half2 h; unsigned u;} v; v.u=u; return v.h; }
__device__ __forceinline__ __half2 f2h2(float a, float b){
  __half2 r; r.x = __float2half_rn(a); r.y = __float2half_rn(b); return r;
}
__device__ __forceinline__ float2 hsum2(__half2 a, __half2 b){
  return make_float2(__low2float(a)+__low2float(b), __high2float(a)+__high2float(b));
}

// ---------------------------------------------------------------------------
// CW[d][c][u*4+k] = b_d[k*256+u] + sum_e ceW[c][e]*Wih_d[k*256+u][e]
__global__ void k_prep_cw(const float* __restrict__ ceW,
                          const float* __restrict__ Wf, const float* __restrict__ bf,
                          const float* __restrict__ Wb, const float* __restrict__ bb,
                          float* __restrict__ CWf, float* __restrict__ CWb){
  const int c = blockIdx.x, u = threadIdx.x;
  const float* Wih  = blockIdx.y ? Wb : Wf;
  const float* bias = blockIdx.y ? bb : bf;
  float*       CW   = blockIdx.y ? CWb : CWf;
  __shared__ float ce[CEn];
  if (u < CEn) ce[u] = ceW[c*CEn + u];
  __syncthreads();
  float a[4];
  #pragma unroll
  for (int k=0;k<4;k++){
    const float* wr = Wih + (size_t)(k*CHn+u)*CEn;
    float s = bias[k*CHn+u];
    #pragma unroll 4
    for (int e=0;e<CEn;e++) s += ce[e]*wr[e];
    a[k]=s;
  }
  ((float4*)CW)[c*CHn+u] = make_float4(a[0],a[1],a[2],a[3]);
}

// packed fp16 Whh: WH[e][u] = { half2(Wi,Wf), half2(Wg,Wo) } ; grid (256,4) x 256
__global__ void k_prep_wt(const float* __restrict__ W0, const float* __restrict__ W1,
                          const float* __restrict__ W2, const float* __restrict__ W3,
                          uint2* __restrict__ T0, uint2* __restrict__ T1,
                          uint2* __restrict__ T2, uint2* __restrict__ T3){
  const int e = blockIdx.x, u = threadIdx.x, w = blockIdx.y;
  const float* Wh = (w==0)?W0:(w==1)?W1:(w==2)?W2:W3;
  uint2*       Tt = (w==0)?T0:(w==1)?T1:(w==2)?T2:T3;
  const float a = Wh[(size_t)(0*CHn+u)*CHn + e];
  const float b = Wh[(size_t)(1*CHn+u)*CHn + e];
  const float c = Wh[(size_t)(2*CHn+u)*CHn + e];
  const float d = Wh[(size_t)(3*CHn+u)*CHn + e];
  uint2 v; v.x = h2u(f2h2(a,b)); v.y = h2u(f2h2(c,d));
  Tt[(size_t)e*CHn+u] = v;
}

// pad word Wih (1024,612) -> (1024,640)
__global__ void k_pad(const float* __restrict__ Wf, const float* __restrict__ Wb,
                      float* __restrict__ Pf, float* __restrict__ Pb){
  const int j = blockIdx.x;
  const float* Win  = blockIdx.y ? Wb : Wf;
  float*       Wout = blockIdx.y ? Pb : Pf;
  for (int col=threadIdx.x; col<DWPn; col+=256)
    Wout[(size_t)j*DWPn+col] = (col<612) ? Win[(size_t)j*612+col] : 0.f;
}

// pad emW (50,512)->(64,512), emb (50)->(64)
__global__ void k_pad_em(const float* __restrict__ emW, const float* __restrict__ emb,
                         float* __restrict__ Wp, float* __restrict__ bp){
  const int j = blockIdx.x;
  for (int col=threadIdx.x; col<512; col+=256)
    Wp[(size_t)j*512+col] = (j<TAGSn) ? emW[(size_t)j*512+col] : 0.f;
  if (threadIdx.x==0) bp[j] = (j<TAGSn) ? emb[j] : 0.f;
}

// stable-compaction ranks from cmakers only; grid (64,2), 64 threads (1 wave)
__global__ void k_prep_pos(const float* __restrict__ cmf, const float* __restrict__ cmb,
                           int* __restrict__ pf, int* __restrict__ pb){
  const float* cm = blockIdx.y ? cmb : cmf;
  int* pos        = blockIdx.y ? pb : pf;
  const int n = blockIdx.x, lane = threadIdx.x;
  int base = 0;
  for (int c=0;c<TCn/64;c++){
    int t = c*64 + lane;
    bool m = cm[n*TCn+t] != 0.f;
    unsigned long long bal = __ballot(m);
    int before = __popcll(bal & ((1ULL<<lane)-1ULL));
    int r = base + before;
    pos[n*TCn+t] = (m && r < Tn) ? r : -1;
    base += __popcll(bal);
  }
}

// ---------------------------------------------------------------------------
// pipelined fp16 hh-dot macros. WH: uint2[(256+8)*256], hpar: &hb2[par][0][0],
// row stride 264 uints. acc[R][2][2] half2.
#define LOADW(W,ec) { _Pragma("unroll") for(int j=0;j<8;j++) \
    (W)[j] = WH[(size_t)(((ec)*8+j)*CHn) + u]; }

#define LOADH2(H,ec) { const unsigned* hp_ = hpar + (ec)*8; \
  (H)[0][0] = *(const uint4*)(hp_);     (H)[0][1] = *(const uint4*)(hp_+4); \
  (H)[1][0] = *(const uint4*)(hp_+264); (H)[1][1] = *(const uint4*)(hp_+268); }

#define LOADH4(H,ec) { const unsigned* hp_ = hpar + (ec)*8; \
  (H)[0][0] = *(const uint4*)(hp_);     (H)[0][1] = *(const uint4*)(hp_+4); \
  (H)[1][0] = *(const uint4*)(hp_+264); (H)[1][1] = *(const uint4*)(hp_+268); \
  (H)[2][0] = *(const uint4*)(hp_+528); (H)[2][1] = *(const uint4*)(hp_+532); \
  (H)[3][0] = *(const uint4*)(hp_+792); (H)[3][1] = *(const uint4*)(hp_+796); }

#define COMP2(W,H) { _Pragma("unroll") for(int j=0;j<8;j++){ \
    const int s_ = j>>2; \
    const __half2 wif_ = u2h((W)[j].x), wgo_ = u2h((W)[j].y); \
    const __half2 h0_ = u2h(((const unsigned*)&(H)[0][0])[j]); \
    const __half2 h1_ = u2h(((const unsigned*)&(H)[1][0])[j]); \
    acc[0][0][s_] = __hfma2(wif_, h0_, acc[0][0][s_]); \
    acc[0][1][s_] = __hfma2(wgo_, h0_, acc[0][1][s_]); \
    acc[1][0][s_] = __hfma2(wif_, h1_, acc[1][0][s_]); \
    acc[1][1][s_] = __hfma2(wgo_, h1_, acc[1][1][s_]); } }

#define COMP4(W,H) { _Pragma("unroll") for(int j=0;j<8;j++){ \
    const int s_ = j>>2; \
    const __half2 wif_ = u2h((W)[j].x), wgo_ = u2h((W)[j].y); \
    _Pragma("unroll") for(int r_=0;r_<4;r_++){ \
      const __half2 hh_ = u2h(((const unsigned*)&(H)[r_][0])[j]); \
      acc[r_][0][s_] = __hfma2(wif_, hh_, acc[r_][0][s_]); \
      acc[r_][1][s_] = __hfma2(wgo_, hh_, acc[r_][1][s_]); } } }

// char LSTM: 64 blocks = 2 dirs x 32 pairs (R=2), 256 threads (unit u)
__global__ __launch_bounds__(256)
void k_char_lstm(const int* __restrict__ cmf, const int* __restrict__ cmb,
                 const float* __restrict__ CWf, const float* __restrict__ CWb,
                 const uint2* __restrict__ WHf, const uint2* __restrict__ WHb,
                 const int* __restrict__ posf, const int* __restrict__ posb,
                 float* __restrict__ sub){
  const int dir = blockIdx.x >> 5, pr = blockIdx.x & 31;
  const int n0 = pr*2, n1 = n0+1;
  const int u = threadIdx.x;
  const int*    cm  = dir ? cmb : cmf;
  const float4* CW  = (const float4*)(dir ? CWb : CWf);
  const uint2*  WH  = dir ? WHb : WHf;
  const int*    pos = dir ? posb : posf;
  const int dofs = dir ? CHn : 0;
  __shared__ unsigned hb2[2][2][264];
  hb2[0][0][u]=0u; hb2[0][1][u]=0u;
  float c0=0.f, c1=0.f;
  int par=0;
  __syncthreads();
  for (int t=0;t<TCn;t++){
    const int ci0 = cm[n0*TCn+t], ci1 = cm[n1*TCn+t];
    float4 z0 = CW[(size_t)ci0*CHn+u];
    float4 z1 = CW[(size_t)ci1*CHn+u];
    const unsigned* hpar = &hb2[par][0][0];
    __half2 acc[2][2][2];
    const __half2 hz = f2h2(0.f,0.f);
    #pragma unroll
    for (int r=0;r<2;r++){ acc[r][0][0]=hz; acc[r][0][1]=hz; acc[r][1][0]=hz; acc[r][1][1]=hz; }
    uint2 wA[8], wB[8];
    uint4 hA[2][2], hB[2][2];
    LOADW(wA,0) LOADH2(hA,0)
    for (int ec=0; ec<32; ec+=2){
      LOADW(wB,ec+1) LOADH2(hB,ec+1)
      COMP2(wA,hA)
      LOADW(wA,ec+2) LOADH2(hA,ec+2)
      COMP2(wB,hB)
    }
    float2 if0 = hsum2(acc[0][0][0],acc[0][0][1]);
    float2 go0 = hsum2(acc[0][1][0],acc[0][1][1]);
    float2 if1 = hsum2(acc[1][0][0],acc[1][0][1]);
    float2 go1 = hsum2(acc[1][1][0],acc[1][1][1]);
    z0.x += if0.x; z0.y += if0.y; z0.z += go0.x; z0.w += go0.y;
    z1.x += if1.x; z1.y += if1.y; z1.z += go1.x; z1.w += go1.y;
    c0 = sigf(z0.y)*c0 + sigf(z0.x)*tanhf(z0.z);
    const float hn0 = sigf(z0.w)*tanhf(c0);
    c1 = sigf(z1.y)*c1 + sigf(z1.x)*tanhf(z1.z);
    const float hn1 = sigf(z1.w)*tanhf(c1);
    hb2[par^1][0][u] = h2u(f2h2(hn0,hn0));
    hb2[par^1][1][u] = h2u(f2h2(hn1,hn1));
    const int p0 = pos[n0*TCn+t];
    if (p0>=0) sub[(size_t)(n0*Tn+p0)*512 + dofs + u] = hn0;
    const int p1 = pos[n1*TCn+t];
    if (p1>=0) sub[(size_t)(n1*Tn+p1)*512 + dofs + u] = hn1;
    __syncthreads();
    par ^= 1;
  }
}

// word LSTM: scans over B=64 steps, batch T=128. 64 blocks = 2 dirs x 32 (R=4)
__global__ __launch_bounds__(256)
void k_word_lstm(const float* __restrict__ wXf, const float* __restrict__ wXb,
                 const uint2* __restrict__ WHf, const uint2* __restrict__ WHb,
                 float* __restrict__ hout){
  const int dir = blockIdx.x >> 5, q = blockIdx.x & 31;
  const int t0 = q*4;
  const int u = threadIdx.x;
  const float* wX = dir ? wXb : wXf;
  const uint2* WH = dir ? WHb : WHf;
  __shared__ unsigned hb2[2][4][264];
  #pragma unroll
  for (int r=0;r<4;r++) hb2[0][r][u]=0u;
  float cst[4] = {0.f,0.f,0.f,0.f};
  int par=0;
  __syncthreads();
  for (int s=0;s<64;s++){
    const int n = dir ? (63-s) : s;
    float4 z[4];
    #pragma unroll
    for (int r=0;r<4;r++){
      const float* xr = wX + (size_t)(n*Tn + t0 + r)*1024 + u;
      z[r] = make_float4(xr[0], xr[256], xr[512], xr[768]);
    }
    const unsigned* hpar = &hb2[par][0][0];
    __half2 acc[4][2][2];
    const __half2 hz = f2h2(0.f,0.f);
    #pragma unroll
    for (int r=0;r<4;r++){ acc[r][0][0]=hz; acc[r][0][1]=hz; acc[r][1][0]=hz; acc[r][1][1]=hz; }
    uint2 wA[8], wB[8];
    uint4 hA[4][2], hB[4][2];
    LOADW(wA,0) LOADH4(hA,0)
    for (int ec=0; ec<32; ec+=2){
      LOADW(wB,ec+1) LOADH4(hB,ec+1)
      COMP4(wA,hA)
      LOADW(wA,ec+2) LOADH4(hA,ec+2)
      COMP4(wB,hB)
    }
    #pragma unroll
    for (int r=0;r<4;r++){
      float2 fi = hsum2(acc[r][0][0],acc[r][0][1]);
      float2 fg = hsum2(acc[r][1][0],acc[r][1][1]);
      float4 zz = z[r];
      zz.x += fi.x; zz.y += fi.y; zz.z += fg.x; zz.w += fg.y;
      cst[r] = sigf(zz.y)*cst[r] + sigf(zz.x)*tanhf(zz.z);
      const float hn = sigf(zz.w)*tanhf(cst[r]);
      hb2[par^1][r][u] = h2u(f2h2(hn,hn));
      hout[(size_t)(n*Tn + t0 + r)*512 + dir*CHn + u] = hn;
    }
    __syncthreads();
    par ^= 1;
  }
}

// ---------------------------------------------------------------------------
// generic fp32 GEMM: C[m][n] = bias[n] + sum_k A[m][k]*W[n][k]
__global__ __launch_bounds__(256)
void k_gemm(const float* __restrict__ A, int lda, int K, int ldw,
            const float* __restrict__ W0, const float* __restrict__ W1,
            const float* __restrict__ b0, const float* __restrict__ b1,
            float* __restrict__ C0, float* __restrict__ C1, int ldc){
  const float* W    = blockIdx.z ? W1 : W0;
  const float* bias = blockIdx.z ? b1 : b0;
  float*       C    = blockIdx.z ? C1 : C0;
  const int m0 = blockIdx.x*128, n0 = blockIdx.y*64;
  __shared__ float As[32][132];
  __shared__ float Bs[32][68];
  const int tid = threadIdx.x;
  float acc[8][4];
  #pragma unroll
  for (int i=0;i<8;i++){
    #pragma unroll
    for (int j=0;j<4;j++) acc[i][j]=0.f;
  }
  const int tm = tid & 15, tn = tid >> 4;
  for (int kc=0; kc<K; kc+=32){
    #pragma unroll
    for (int it=0; it<4; it++){
      int fl = tid + it*256; int r = fl>>3; int kq = fl&7;
      float4 v = *(const float4*)(A + (size_t)(m0+r)*lda + kc + kq*4);
      As[kq*4+0][r]=v.x; As[kq*4+1][r]=v.y; As[kq*4+2][r]=v.z; As[kq*4+3][r]=v.w;
    }
    #pragma unroll
    for (int it=0; it<2; it++){
      int fl = tid + it*256; int r = fl>>3; int kq = fl&7;
      float4 v = *(const float4*)(W + (size_t)(n0+r)*ldw + kc + kq*4);
      Bs[kq*4+0][r]=v.x; Bs[kq*4+1][r]=v.y; Bs[kq*4+2][r]=v.z; Bs[kq*4+3][r]=v.w;
    }
    __syncthreads();
    #pragma unroll
    for (int k=0;k<32;k++){
      float a[8], b[4];
      *(float4*)(a)   = *(const float4*)(&As[k][tm*8]);
      *(float4*)(a+4) = *(const float4*)(&As[k][tm*8+4]);
      *(float4*)(b)   = *(const float4*)(&Bs[k][tn*4]);
      #pragma unroll
      for (int i=0;i<8;i++){
        #pragma unroll
        for (int j=0;j<4;j++) acc[i][j] += a[i]*b[j];
      }
    }
    __syncthreads();
  }
  float4 bv = *(const float4*)(bias + n0 + tn*4);
  #pragma unroll
  for (int i=0;i<8;i++){
    float4 o = make_float4(acc[i][0]+bv.x, acc[i][1]+bv.y, acc[i][2]+bv.z, acc[i][3]+bv.w);
    *(float4*)(C + (size_t)(m0+tm*8+i)*ldc + n0 + tn*4) = o;
  }
}

// highway elementwise: sub = g*relu(zt) + (1-g)*sub
__global__ __launch_bounds__(256)
void k_hwelt(const float* __restrict__ hwz, float* __restrict__ sub){
  const int idx = blockIdx.x*256 + threadIdx.x;
  const int m = idx >> 7, j4 = idx & 127;
  float4 s  = ((const float4*)sub)[idx];
  float4 zt = ((const float4*)hwz)[(size_t)m*256 + j4];
  float4 zg = ((const float4*)hwz)[(size_t)m*256 + 128 + j4];
  float4 o;
  { float g=sigf(zg.x), tr=fmaxf(zt.x,0.f); o.x = g*tr + (1.f-g)*s.x; }
  { float g=sigf(zg.y), tr=fmaxf(zt.y,0.f); o.y = g*tr + (1.f-g)*s.y; }
  { float g=sigf(zg.z), tr=fmaxf(zt.z,0.f); o.z = g*tr + (1.f-g)*s.z; }
  { float g=sigf(zg.w), tr=fmaxf(zt.w,0.f); o.w = g*tr + (1.f-g)*s.w; }
  ((float4*)sub)[idx] = o;
}

// assemble padded word input
__global__ void k_wasm(const int* __restrict__ wmap, const float* __restrict__ weW,
                       const float* __restrict__ sub, float* __restrict__ w){
  const int m = blockIdx.x;
  const int wi = wmap[m];
  for (int col=threadIdx.x; col<DWPn; col+=256){
    float v = 0.f;
    if (col < 100)      v = weW[(size_t)wi*100 + col];
    else if (col < 612) v = sub[(size_t)m*512 + (col-100)];
    w[(size_t)m*DWPn + col] = v;
  }
}

// crf[m][a][b] = em[m][b] + trans[a][b] ; em ld=64
__global__ __launch_bounds__(256)
void k_crf(const float* __restrict__ em, const float* __restrict__ trans,
           float* __restrict__ out){
  const int m = blockIdx.x;
  __shared__ float er[TAGSn];
  if (threadIdx.x < TAGSn) er[threadIdx.x] = em[(size_t)m*64 + threadIdx.x];
  __syncthreads();
  float* o = out + (size_t)m*2500;
  for (int r=threadIdx.x; r<2500; r+=256)
    o[r] = er[r % TAGSn] + trans[r];
}

// int tail outputs as floats
__global__ void k_tail(const int* __restrict__ tm, const int* __restrict__ ln,
                       const int* __restrict__ tc, float* __restrict__ out){
  const int i = blockIdx.x*256 + threadIdx.x;
  if (i < 8192)       out[i] = (float)tm[i];
  else if (i < 8256)  out[i] = (float)ln[i-8192];
  else if (i < 16448) out[i] = (float)tc[i-8256];
}

// ---------------------------------------------------------------------------
extern "C" void kernel_launch(void* const* d_in, const int* in_sizes, int n_in,
                              void* d_out, int out_size, void* d_ws, size_t ws_size,
                              hipStream_t stream){
  (void)in_sizes; (void)n_in; (void)out_size; (void)ws_size;
  const int*   wmap   = (const int*)d_in[0];
  const int*   cmapsf = (const int*)d_in[1];
  const int*   cmapsb = (const int*)d_in[2];
  const float* cmakf  = (const float*)d_in[3];
  const float* cmakb  = (const float*)d_in[4];
  const int*   tmaps  = (const int*)d_in[5];
  const int*   tmapc  = (const int*)d_in[6];
  const int*   lengths= (const int*)d_in[7];
  const float* ceW    = (const float*)d_in[8];
  const float* fcWih  = (const float*)d_in[9];
  const float* fcWhh  = (const float*)d_in[10];
  const float* fcb    = (const float*)d_in[11];
  const float* bcWih  = (const float*)d_in[12];
  const float* bcWhh  = (const float*)d_in[13];
  const float* bcb    = (const float*)d_in[14];
  const float* weW    = (const float*)d_in[15];
  const float* wfWih  = (const float*)d_in[16];
  const float* wfWhh  = (const float*)d_in[17];
  const float* wfb    = (const float*)d_in[18];
  const float* wbWih  = (const float*)d_in[19];
  const float* wbWhh  = (const float*)d_in[20];
  const float* wbb    = (const float*)d_in[21];
  const float* hwWt   = (const float*)d_in[22];
  const float* hwbt   = (const float*)d_in[23];
  const float* hwWg   = (const float*)d_in[24];
  const float* hwbg   = (const float*)d_in[25];
  const float* emW    = (const float*)d_in[26];
  const float* emb    = (const float*)d_in[27];
  const float* trans  = (const float*)d_in[28];

  // workspace layout (floats)
  float* p = (float*)d_ws;
  size_t o = 0;
  float* CWf  = p + o; o += 100*1024;
  float* CWb  = p + o; o += 100*1024;
  uint2* WHcf = (uint2*)(p + o); o += 264*256*2;
  uint2* WHcb = (uint2*)(p + o); o += 264*256*2;
  uint2* WHwf = (uint2*)(p + o); o += 264*256*2;
  uint2* WHwb = (uint2*)(p + o); o += 264*256*2;
  float* Wpf  = p + o; o += 1024*DWPn;
  float* Wpb  = p + o; o += 1024*DWPn;
  int*   posf = (int*)(p + o); o += 64*512;
  int*   posb = (int*)(p + o); o += 64*512;
  float* sub  = p + o; o += (size_t)64*128*512;   // reused later as hout
  float* hwz  = p + o; o += (size_t)8192*1024;    // reused later as wXf
  float* wq   = p + o; o += (size_t)8192*DWPn;    // reused later as em/emWp/embp
  float* wXb  = p + o; o += (size_t)8192*1024;
  float* wXf  = hwz;            // alias: hwz dead after k_hwelt
  float* hout = sub;            // alias: sub dead after k_wasm
  float* em   = wq;             // alias: wq dead after word-Xih gemm
  float* emWp = wq + 8192*64;
  float* embp = emWp + 64*512;

  float* out  = (float*)d_out;

  hipMemsetAsync(sub, 0, (size_t)64*128*512*sizeof(float), stream);

  k_prep_cw <<<dim3(100,2), 256, 0, stream>>>(ceW, fcWih, fcb, bcWih, bcb, CWf, CWb);
  k_prep_wt <<<dim3(256,4), 256, 0, stream>>>(fcWhh, bcWhh, wfWhh, wbWhh, WHcf, WHcb, WHwf, WHwb);
  k_pad     <<<dim3(1024,2), 256, 0, stream>>>(wfWih, wbWih, Wpf, Wpb);
  k_prep_pos<<<dim3(64,2), 64, 0, stream>>>(cmakf, cmakb, posf, posb);

  k_char_lstm<<<64, 256, 0, stream>>>(cmapsf, cmapsb, CWf, CWb, WHcf, WHcb, posf, posb, sub);

  // highway
  k_gemm<<<dim3(64,8,2), 256, 0, stream>>>(sub, 512, 512, 512,
                                           hwWt, hwWg, hwbt, hwbg,
                                           hwz, hwz+512, 1024);
  k_hwelt<<<4096, 256, 0, stream>>>(hwz, sub);

  k_wasm<<<8192, 256, 0, stream>>>(wmap, weW, sub, wq);

  // word input projections
  k_gemm<<<dim3(64,16,2), 256, 0, stream>>>(wq, DWPn, DWPn, DWPn,
                                            Wpf, Wpb, wfb, wbb,
                                            wXf, wXb, 1024);

  k_word_lstm<<<64, 256, 0, stream>>>(wXf, wXb, WHwf, WHwb, hout);

  // em = hout @ emW^T + emb (padded to 64 tags), ld 64
  k_pad_em<<<64, 256, 0, stream>>>(emW, emb, emWp, embp);
  k_gemm<<<dim3(64,1,1), 256, 0, stream>>>(hout, 512, 512, 512,
                                           emWp, emWp, embp, embp,
                                           em, em, 64);

  k_crf<<<8192, 256, 0, stream>>>(em, trans, out);
  k_tail<<<65, 256, 0, stream>>>(tmaps, lengths, tmapc, out + (size_t)20480000);
}